// Round 8
// baseline (2311.029 us; speedup 1.0000x reference)
//
#include <hip/hip_runtime.h>
#include <hip/hip_bf16.h>
#include <math.h>

// GraphCast processor, round 8.
// R8: barrier-free MFMA GEMM. R5/R6 counters showed the LDS-staged GEMM is
// barrier-drain-bound (MfmaUtil 4.4%, VALUBusy 7.7%, occ 17%): with K=256/512
// there are only 8-16 k-tiles and all 4 waves gang-stall on vmcnt(0)+s_barrier
// every tile. MFMA A/B fragments are directly loadable from row-major A (8
// contiguous fp32/lane) and BT (16B/lane) -> no LDS, no __syncthreads; each
// wave is an independent 64x64 stream, compiler free to overlap k-iterations.
// B (<=512KB) is L2-resident across all m-blocks; A intra-block reuse via L1.
// node_agg: exact R2 version (76us, VGPR 36, occ 51% -- beat both "clever"
// variants which lost on occupancy).

#define NNODES 40962
#define NEDGES 163848
#define NLAYERS 6

typedef __attribute__((ext_vector_type(8))) short short8;
typedef __attribute__((ext_vector_type(4))) float f32x4;

union pack8 { uint4 u4; short8 s8; };

// 8 fp32 -> bf16 hi/lo split (truncation split; hi+lo ~ 16-bit mantissa)
__device__ __forceinline__ void split8(const float* f, short8& hi, short8& lo) {
    unsigned int h[4], l[4];
    #pragma unroll
    for (int i = 0; i < 4; ++i) {
        unsigned int u0 = __float_as_uint(f[2 * i]);
        unsigned int u1 = __float_as_uint(f[2 * i + 1]);
        float l0 = f[2 * i]     - __uint_as_float(u0 & 0xFFFF0000u);
        float l1 = f[2 * i + 1] - __uint_as_float(u1 & 0xFFFF0000u);
        h[i] = (u0 >> 16) | (u1 & 0xFFFF0000u);
        l[i] = (__float_as_uint(l0) >> 16) | (__float_as_uint(l1) & 0xFFFF0000u);
    }
    pack8 ph, pl;
    ph.u4 = make_uint4(h[0], h[1], h[2], h[3]);
    pl.u4 = make_uint4(l[0], l[1], l[2], l[3]);
    hi = ph.s8; lo = pl.s8;
}

// ---------------- weight prep: transpose fp32 [R][C] -> bf16(RNE) [C][R] ----------------
__global__ __launch_bounds__(256) void wprep_kernel(
    const float* __restrict__ src, unsigned short* __restrict__ dst,
    int R, int C, size_t src_lstride, size_t src_hstride, int halves)
{
    __shared__ float t[32][33];
    const int b = blockIdx.z;
    src += (size_t)(b / halves) * src_lstride + (size_t)(b % halves) * src_hstride;
    dst += (size_t)b * R * C;
    const int tx = threadIdx.x & 31, ty = threadIdx.x >> 5;
    const int c0 = blockIdx.x * 32, r0 = blockIdx.y * 32;
    #pragma unroll
    for (int i = 0; i < 4; ++i)
        t[ty + 8 * i][tx] = src[(size_t)(r0 + ty + 8 * i) * C + c0 + tx];
    __syncthreads();
    #pragma unroll
    for (int i = 0; i < 4; ++i) {
        unsigned int u = __float_as_uint(t[tx][ty + 8 * i]);
        unsigned short h = (unsigned short)((u + 0x7FFFu + ((u >> 16) & 1u)) >> 16); // RNE
        dst[(size_t)(c0 + ty + 8 * i) * R + r0 + tx] = h;
    }
}

// ---------------- barrier-free MFMA GEMM ----------------
// C = (A1 K-concat A2) @ BT^T (+bias) (+resid); optional LN+SiLU on A
// (lnstats/lng/lnb). A fp32 row-major ld=256; BT bf16 [cols][K].
// Block 256 = 4 independent waves; wave (wm,wn) computes 64x64 of the
// 128x128 block tile. No LDS, no barriers.
__global__ __launch_bounds__(256) void gemm_mfma(
    const float* __restrict__ A1, const float* __restrict__ A2,
    const unsigned short* __restrict__ BT,
    const float* __restrict__ bias, const float* __restrict__ resid,
    const float2* __restrict__ lnstats, const float* __restrict__ lng,
    const float* __restrict__ lnb,
    float* __restrict__ C, int M, int K, int ldC)
{
    const int tid = threadIdx.x;
    const int wave = tid >> 6, lane = tid & 63;
    const int m0 = blockIdx.x * 128, n0 = blockIdx.y * 128;
    const int wm = wave >> 1, wn = wave & 1;
    const int fm = lane & 15, quad = lane >> 4, ko = quad * 8;

    // A-frag rows (clamped; clamped rows are discarded at store)
    int arow[4];
    float2 st[4];
    #pragma unroll
    for (int i = 0; i < 4; ++i) {
        int r = m0 + wm * 64 + i * 16 + fm;
        arow[i] = (r < M) ? r : (M - 1);
        st[i] = lnstats ? lnstats[arow[i]] : make_float2(0.f, 0.f);
    }
    // B-frag row pointers
    const unsigned short* brow[4];
    #pragma unroll
    for (int j = 0; j < 4; ++j)
        brow[j] = BT + (size_t)(n0 + wn * 64 + j * 16 + fm) * K;

    f32x4 acc[4][4];
    #pragma unroll
    for (int i = 0; i < 4; ++i)
        #pragma unroll
        for (int j = 0; j < 4; ++j)
            acc[i][j] = (f32x4){0.f, 0.f, 0.f, 0.f};

    const int nkt = K >> 5;
    for (int kt = 0; kt < nkt; ++kt) {
        const int k0 = kt << 5;
        const float* Asrc; int kb;
        if (A2 != nullptr && k0 >= 256) { Asrc = A2; kb = k0 - 256; }
        else                            { Asrc = A1; kb = k0; }

        short8 bf[4];
        #pragma unroll
        for (int j = 0; j < 4; ++j)
            bf[j] = *(const short8*)(brow[j] + k0 + ko);

        float gg[8], bb[8];
        if (lnstats) {
            f32x4 g0 = *(const f32x4*)(lng + k0 + ko);
            f32x4 g1 = *(const f32x4*)(lng + k0 + ko + 4);
            f32x4 b0 = *(const f32x4*)(lnb + k0 + ko);
            f32x4 b1 = *(const f32x4*)(lnb + k0 + ko + 4);
            gg[0]=g0.x; gg[1]=g0.y; gg[2]=g0.z; gg[3]=g0.w;
            gg[4]=g1.x; gg[5]=g1.y; gg[6]=g1.z; gg[7]=g1.w;
            bb[0]=b0.x; bb[1]=b0.y; bb[2]=b0.z; bb[3]=b0.w;
            bb[4]=b1.x; bb[5]=b1.y; bb[6]=b1.z; bb[7]=b1.w;
        }

        short8 afh[4], afl[4];
        #pragma unroll
        for (int i = 0; i < 4; ++i) {
            const float* ap = Asrc + (size_t)arow[i] * 256 + kb + ko;
            f32x4 v0 = *(const f32x4*)ap;
            f32x4 v1 = *(const f32x4*)(ap + 4);
            float f[8] = {v0.x, v0.y, v0.z, v0.w, v1.x, v1.y, v1.z, v1.w};
            if (lnstats) {
                #pragma unroll
                for (int t = 0; t < 8; ++t) {
                    float y = (f[t] - st[i].x) * st[i].y * gg[t] + bb[t];
                    f[t] = y / (1.0f + __expf(-y));
                }
            }
            split8(f, afh[i], afl[i]);
        }

        #pragma unroll
        for (int i = 0; i < 4; ++i)
            #pragma unroll
            for (int j = 0; j < 4; ++j) {
                acc[i][j] = __builtin_amdgcn_mfma_f32_16x16x32_bf16(afl[i], bf[j], acc[i][j], 0, 0, 0);
                acc[i][j] = __builtin_amdgcn_mfma_f32_16x16x32_bf16(afh[i], bf[j], acc[i][j], 0, 0, 0);
            }
    }

    // epilogue: C/D layout col=lane&15, row=quad*4+reg
    #pragma unroll
    for (int j = 0; j < 4; ++j) {
        const int gc = n0 + wn * 64 + j * 16 + fm;
        const float bj = bias ? bias[gc] : 0.f;
        #pragma unroll
        for (int i = 0; i < 4; ++i) {
            #pragma unroll
            for (int r = 0; r < 4; ++r) {
                const int gr = m0 + wm * 64 + i * 16 + quad * 4 + r;
                if (gr < M) {
                    float v = acc[i][j][r] + bj;
                    if (resid) v += resid[(size_t)gr * ldC + gc];
                    C[(size_t)gr * ldC + gc] = v;
                }
            }
        }
    }
}

__device__ __forceinline__ float wave_sum(float v) {
    #pragma unroll
    for (int o = 32; o > 0; o >>= 1) v += __shfl_xor(v, o);
    return v;
}

// ---------------- CSR build (once per launch) ----------------
__global__ __launch_bounds__(256) void count_kernel(
    const int* __restrict__ dst, int* __restrict__ deg, int E)
{
    int e = blockIdx.x * 256 + threadIdx.x;
    if (e < E) atomicAdd(&deg[dst[e]], 1);
}

__global__ __launch_bounds__(1024) void scan_kernel(
    const int* __restrict__ deg, int* __restrict__ rowptr, int n)
{
    __shared__ int wsum[16];
    __shared__ int carry_s;
    const int tid = threadIdx.x;
    const int lane = tid & 63, wave = tid >> 6;
    if (tid == 0) carry_s = 0;
    __syncthreads();

    for (int base = 0; base < n; base += 1024) {
        int i = base + tid;
        int v = (i < n) ? deg[i] : 0;
        int x = v;
        #pragma unroll
        for (int o = 1; o < 64; o <<= 1) {
            int t = __shfl_up(x, o);
            if (lane >= o) x += t;
        }
        if (lane == 63) wsum[wave] = x;
        __syncthreads();
        if (wave == 0 && lane < 16) {
            int w = wsum[lane];
            #pragma unroll
            for (int o = 1; o < 16; o <<= 1) {
                int t = __shfl_up(w, o);
                if (lane >= o) w += t;
            }
            wsum[lane] = w;
        }
        __syncthreads();
        int wave_off = (wave == 0) ? 0 : wsum[wave - 1];
        int incl = x + wave_off + carry_s;
        if (i < n) rowptr[i] = incl - v;
        __syncthreads();
        if (tid == 0) carry_s += wsum[15];
        __syncthreads();
    }
    if (tid == 0) rowptr[n] = carry_s;
}

__global__ __launch_bounds__(256) void scatter_kernel(
    const int* __restrict__ dst, int* __restrict__ cursor,
    int* __restrict__ esorted, int E)
{
    int e = blockIdx.x * 256 + threadIdx.x;
    if (e < E) {
        int p = atomicAdd(&cursor[dst[e]], 1);
        esorted[p] = e;
    }
}

// ---------------- fused per-node message + aggregate (R2 measured-best) ----------------
__global__ __launch_bounds__(256) void node_agg_kernel(
    const float* __restrict__ P,      // [N,512]
    const int* __restrict__ src,
    const float* __restrict__ attr,   // [E,4]
    const float* __restrict__ W3,     // [4,256]
    const float* __restrict__ be, const float* __restrict__ g1, const float* __restrict__ b1,
    const int* __restrict__ rowptr, const int* __restrict__ esorted,
    float* __restrict__ agg, int N)
{
    const int wave = threadIdx.x >> 6;
    const int lane = threadIdx.x & 63;
    const int n = blockIdx.x * 4 + wave;
    if (n >= N) return;
    const int c0 = lane * 4;

    float4 p1 = *(const float4*)(P + (size_t)n * 512 + c0);
    const float* p1p = (const float*)&p1;

    float w30[4], w31[4], w32[4], w33[4], bev[4], g1v[4], b1v[4];
    #pragma unroll
    for (int i = 0; i < 4; ++i) {
        const int c = c0 + i;
        w30[i] = W3[c]; w31[i] = W3[256 + c]; w32[i] = W3[512 + c]; w33[i] = W3[768 + c];
        bev[i] = be[c]; g1v[i] = g1[c]; b1v[i] = b1[c];
    }

    float acc[4] = {0.f, 0.f, 0.f, 0.f};
    const int beg = rowptr[n];
    const int end = rowptr[n + 1];

    for (int i = beg; i < end; ++i) {
        const int e = esorted[i];
        const int s = src[e];
        float4 ps = *(const float4*)(P + (size_t)s * 512 + 256 + c0);
        const float* psp = (const float*)&ps;
        float4 av = *(const float4*)(attr + (size_t)e * 4);

        float h[4];
        #pragma unroll
        for (int j = 0; j < 4; ++j) {
            float w = av.x * w30[j] + av.y * w31[j] + av.z * w32[j] + av.w * w33[j];
            h[j] = p1p[j] + psp[j] + w + bev[j];
        }

        float sum = wave_sum(h[0] + h[1] + h[2] + h[3]);
        const float mean = sum * (1.0f / 256.0f);
        float vs = 0.f;
        #pragma unroll
        for (int j = 0; j < 4; ++j) { float t = h[j] - mean; vs += t * t; }
        vs = wave_sum(vs);
        const float rstd = rsqrtf(vs * (1.0f / 256.0f) + 1e-5f);

        #pragma unroll
        for (int j = 0; j < 4; ++j) {
            float y = (h[j] - mean) * rstd * g1v[j] + b1v[j];
            acc[j] += y / (1.0f + __expf(-y));
        }
    }

    *(float4*)(agg + (size_t)n * 256 + c0) = make_float4(acc[0], acc[1], acc[2], acc[3]);
}

// Per-row mean/rstd of u [N,256] -> stats[N]. One wave per row.
__global__ __launch_bounds__(256) void row_stats_kernel(
    const float* __restrict__ u, float2* __restrict__ stats, int N)
{
    const int wave = threadIdx.x >> 6;
    const int lane = threadIdx.x & 63;
    const int r = blockIdx.x * 4 + wave;
    if (r >= N) return;

    float4 hv = *(const float4*)(u + (size_t)r * 256 + lane * 4);
    float s_ = (hv.x + hv.y) + (hv.z + hv.w);
    float q_ = (hv.x * hv.x + hv.y * hv.y) + (hv.z * hv.z + hv.w * hv.w);
    #pragma unroll
    for (int o = 32; o > 0; o >>= 1) {
        s_ += __shfl_xor(s_, o);
        q_ += __shfl_xor(q_, o);
    }
    if (lane == 0) {
        const float mean = s_ * (1.0f / 256.0f);
        const float var  = q_ * (1.0f / 256.0f) - mean * mean;
        stats[r] = make_float2(mean, rsqrtf(var + 1e-5f));
    }
}

extern "C" void kernel_launch(void* const* d_in, const int* in_sizes, int n_in,
                              void* d_out, int out_size, void* d_ws, size_t ws_size,
                              hipStream_t stream) {
    const float* mesh   = (const float*)d_in[0];
    const int*   eidx   = (const int*)  d_in[1];
    const float* eattr  = (const float*)d_in[2];
    const float* We_w   = (const float*)d_in[3];
    const float* We_b   = (const float*)d_in[4];
    const float* ln1_g  = (const float*)d_in[5];
    const float* ln1_b  = (const float*)d_in[6];
    const float* Wn1_w  = (const float*)d_in[7];
    const float* Wn1_b  = (const float*)d_in[8];
    const float* ln2_g  = (const float*)d_in[9];
    const float* ln2_b  = (const float*)d_in[10];
    const float* Wn2_w  = (const float*)d_in[11];
    const float* Wn2_b  = (const float*)d_in[12];

    const int N = NNODES, E = NEDGES;

    float* x   = (float*)d_out;                 // [N,256]
    float* P   = (float*)d_ws;                  // [N,512]
    float* u   = P;                             // [N,256] aliases P
    float* agg = P + (size_t)N * 512;           // [N,256]
    int*   deg     = (int*)(agg + (size_t)N * 256);
    int*   rowptr  = deg + N;
    int*   cursor  = rowptr + (N + 1);
    int*   esorted = cursor + N;                // E
    uintptr_t wp = (uintptr_t)(esorted + E);
    wp = (wp + 63) & ~(uintptr_t)63;
    unsigned short* BTe  = (unsigned short*)wp;            // [6][512][256]
    unsigned short* BTn1 = BTe  + (size_t)6 * 512 * 256;   // [6][256][512]
    unsigned short* BTn2 = BTn1 + (size_t)6 * 256 * 512;   // [6][256][256]
    float2* stats = (float2*)(BTn2 + (size_t)6 * 256 * 256);  // [N]

    const int* src = eidx;
    const int* dst = eidx + E;

    hipMemcpyAsync(x, mesh, (size_t)N * 256 * sizeof(float),
                   hipMemcpyDeviceToDevice, stream);

    // ---- weight prep ----
    wprep_kernel<<<dim3(8, 8, 12), 256, 0, stream>>>(
        We_w, BTe, 256, 256, (size_t)516 * 256, (size_t)256 * 256, 2);
    wprep_kernel<<<dim3(8, 16, 6), 256, 0, stream>>>(
        Wn1_w, BTn1, 512, 256, (size_t)512 * 256, 0, 1);
    wprep_kernel<<<dim3(8, 8, 6), 256, 0, stream>>>(
        Wn2_w, BTn2, 256, 256, (size_t)256 * 256, 0, 1);

    // ---- CSR build ----
    hipMemsetAsync(deg, 0, (size_t)N * sizeof(int), stream);
    count_kernel<<<(E + 255) / 256, 256, 0, stream>>>(dst, deg, E);
    scan_kernel<<<1, 1024, 0, stream>>>(deg, rowptr, N);
    hipMemcpyAsync(cursor, rowptr, (size_t)N * sizeof(int),
                   hipMemcpyDeviceToDevice, stream);
    scatter_kernel<<<(E + 255) / 256, 256, 0, stream>>>(dst, cursor, esorted, E);

    const int mblocks = (N + 127) / 128;
    const int node_blocks = (N + 3) / 4;

    for (int l = 0; l < NLAYERS; ++l) {
        const float* W3  = We_w + (size_t)l * 516 * 256 + (size_t)512 * 256;
        const float* be  = We_b  + (size_t)l * 256;
        const float* g1  = ln1_g + (size_t)l * 256;
        const float* b1  = ln1_b + (size_t)l * 256;
        const float* bn1 = Wn1_b + (size_t)l * 256;
        const float* g2  = ln2_g + (size_t)l * 256;
        const float* b2  = ln2_b + (size_t)l * 256;
        const float* bn2 = Wn2_b + (size_t)l * 256;
        const unsigned short* bte  = BTe  + (size_t)l * 512 * 256;
        const unsigned short* btn1 = BTn1 + (size_t)l * 256 * 512;
        const unsigned short* btn2 = BTn2 + (size_t)l * 256 * 256;

        // P = x @ [W1|W2]  -> [N,512]
        gemm_mfma<<<dim3(mblocks, 4), 256, 0, stream>>>(
            x, nullptr, bte, nullptr, nullptr, nullptr, nullptr, nullptr,
            P, N, 256, 512);
        // agg
        node_agg_kernel<<<node_blocks, 256, 0, stream>>>(
            P, src, eattr, W3, be, g1, b1, rowptr, esorted, agg, N);
        // u = [x | agg] @ Wn1 + bn1
        gemm_mfma<<<dim3(mblocks, 2), 256, 0, stream>>>(
            x, agg, btn1, bn1, nullptr, nullptr, nullptr, nullptr,
            u, N, 512, 256);
        // stats of u rows
        row_stats_kernel<<<node_blocks, 256, 0, stream>>>(u, stats, N);
        // x = x + silu(LN(u)) @ Wn2 + bn2   (LN+SiLU fused into A-loads)
        gemm_mfma<<<dim3(mblocks, 2), 256, 0, stream>>>(
            u, nullptr, btn2, bn2, x, stats, g2, b2,
            x, N, 256, 256);
    }
}

// Round 9
// 1548.559 us; speedup vs baseline: 1.4924x; 1.4924x over previous
//
#include <hip/hip_runtime.h>
#include <hip/hip_bf16.h>
#include <math.h>

// GraphCast processor, round 9.
// Base = R2 configuration exactly (measured best, 1527us): LDS-staged MFMA GEMM
// with fp32 A + hi/lo bf16 split in staging; simple one-wave-per-node node_agg
// (76us, VGPR 36); separate ln_silu kernel.
// R9 single change: P stored as bf16 (RNE). P only feeds h -> LayerNorm, so
// bf16 rounding ~ the already-tolerated bf16-B rounding. Halves P-GEMM write
// (84->42MB) and halves cache lines touched by node_agg's random gathers
// (latency/transaction-bound at 2.1TB/s).
// R5-R8 lessons (all regressed): pure-async staging loses the free VALU
// latency-fill; no-LDS GEMM loses B-sharing between waves; fancy node_agg
// variants lose on VGPR/occupancy.

#define NNODES 40962
#define NEDGES 163848
#define NLAYERS 6

typedef __attribute__((ext_vector_type(8))) short short8;
typedef __attribute__((ext_vector_type(4))) float f32x4;

__device__ __forceinline__ void async_copy16(void* lds, const void* g) {
    __builtin_amdgcn_global_load_lds(
        (const __attribute__((address_space(1))) unsigned int*)g,
        (__attribute__((address_space(3))) unsigned int*)lds, 16, 0, 0);
}

__device__ __forceinline__ float bf2f(unsigned short v) {
    return __uint_as_float(((unsigned int)v) << 16);
}
__device__ __forceinline__ unsigned short f2bf_rne(float v) {
    unsigned int u = __float_as_uint(v);
    return (unsigned short)((u + 0x7FFFu + ((u >> 16) & 1u)) >> 16);
}

// ---------------- weight prep: transpose fp32 [R][C] -> bf16(RNE) [C][R] ----------------
__global__ __launch_bounds__(256) void wprep_kernel(
    const float* __restrict__ src, unsigned short* __restrict__ dst,
    int R, int C, size_t src_lstride, size_t src_hstride, int halves)
{
    __shared__ float t[32][33];
    const int b = blockIdx.z;
    src += (size_t)(b / halves) * src_lstride + (size_t)(b % halves) * src_hstride;
    dst += (size_t)b * R * C;
    const int tx = threadIdx.x & 31, ty = threadIdx.x >> 5;
    const int c0 = blockIdx.x * 32, r0 = blockIdx.y * 32;
    #pragma unroll
    for (int i = 0; i < 4; ++i)
        t[ty + 8 * i][tx] = src[(size_t)(r0 + ty + 8 * i) * C + c0 + tx];
    __syncthreads();
    #pragma unroll
    for (int i = 0; i < 4; ++i)
        dst[(size_t)(c0 + ty + 8 * i) * R + r0 + tx] = f2bf_rne(t[tx][ty + 8 * i]);
}

// ---------------- MFMA GEMM (R2 structure) ----------------
// C = (A1 K-concat A2) @ BT^T (+bias) (+resid). A fp32 ld=256; BT bf16 [cols][K].
// Output: fp32 C, or bf16 Cbf (RNE) if Cbf != null.
__global__ __launch_bounds__(256) void gemm_mfma(
    const float* __restrict__ A1, const float* __restrict__ A2,
    const unsigned short* __restrict__ BT,
    const float* __restrict__ bias, const float* __restrict__ resid,
    float* __restrict__ C, unsigned short* __restrict__ Cbf,
    int M, int K, int ldC)
{
    __shared__ __align__(16) short Ah[128 * 40];
    __shared__ __align__(16) short Al[128 * 40];
    __shared__ __align__(16) short Bs[128 * 32];

    const int tid = threadIdx.x;
    const int wave = tid >> 6;
    const int lane = tid & 63;
    const int m0 = blockIdx.x * 128;
    const int n0 = blockIdx.y * 128;
    const int wm = wave >> 1;
    const int wn = wave & 1;
    const int fm = lane & 15;
    const int quad = lane >> 4;
    const int ko = quad * 8;

    const int arow = tid >> 1;
    const int akh = (tid & 1) * 16;
    const int gr_stage = m0 + arow;

    f32x4 acc[4][4];
    #pragma unroll
    for (int i = 0; i < 4; ++i)
        #pragma unroll
        for (int j = 0; j < 4; ++j)
            acc[i][j] = (f32x4){0.f, 0.f, 0.f, 0.f};

    const int nkt = K >> 5;
    for (int kt = 0; kt < nkt; ++kt) {
        const int k0 = kt << 5;
        const float* Asrc; int kb;
        if (A2 != nullptr && k0 >= 256) { Asrc = A2; kb = k0 - 256; }
        else                            { Asrc = A1; kb = k0; }

        // --- B: async global->LDS ---
        {
            const int n_row = wave * 32 + (lane >> 2);
            const char* gbase = (const char*)BT + (((size_t)(n0 + n_row) * K + k0) << 1)
                              + ((lane & 3) << 4);
            char* lbase = (char*)Bs + wave * 2048;
            async_copy16(lbase, gbase);
            const char* gbase2 = gbase + ((size_t)16 * K << 1);
            async_copy16(lbase + 1024, gbase2);
        }

        // --- A: fp32 load -> hi/lo bf16 split -> LDS (VALU fills staging latency) ---
        {
            float f[16];
            if (gr_stage < M) {
                const float* ap = Asrc + (size_t)gr_stage * 256 + kb + akh;
                #pragma unroll
                for (int i = 0; i < 4; ++i) {
                    f32x4 v = *(const f32x4*)(ap + 4 * i);
                    f[4 * i + 0] = v.x; f[4 * i + 1] = v.y;
                    f[4 * i + 2] = v.z; f[4 * i + 3] = v.w;
                }
            } else {
                #pragma unroll
                for (int i = 0; i < 16; ++i) f[i] = 0.f;
            }
            unsigned int hid[8], lod[8];
            #pragma unroll
            for (int i = 0; i < 8; ++i) {
                unsigned int u0 = __float_as_uint(f[2 * i]);
                unsigned int u1 = __float_as_uint(f[2 * i + 1]);
                float l0 = f[2 * i]     - __uint_as_float(u0 & 0xFFFF0000u);
                float l1 = f[2 * i + 1] - __uint_as_float(u1 & 0xFFFF0000u);
                hid[i] = (u0 >> 16) | (u1 & 0xFFFF0000u);
                lod[i] = (__float_as_uint(l0) >> 16) | (__float_as_uint(l1) & 0xFFFF0000u);
            }
            short* ah = &Ah[arow * 40 + akh];
            short* al = &Al[arow * 40 + akh];
            ((uint4*)ah)[0] = make_uint4(hid[0], hid[1], hid[2], hid[3]);
            ((uint4*)ah)[1] = make_uint4(hid[4], hid[5], hid[6], hid[7]);
            ((uint4*)al)[0] = make_uint4(lod[0], lod[1], lod[2], lod[3]);
            ((uint4*)al)[1] = make_uint4(lod[4], lod[5], lod[6], lod[7]);
        }

        __syncthreads();

        short8 afh[4], afl[4], bf[4];
        #pragma unroll
        for (int i = 0; i < 4; ++i) {
            const int r = wm * 64 + i * 16 + fm;
            afh[i] = *(const short8*)&Ah[r * 40 + ko];
            afl[i] = *(const short8*)&Al[r * 40 + ko];
        }
        #pragma unroll
        for (int j = 0; j < 4; ++j) {
            const int r = wn * 64 + j * 16 + fm;
            bf[j] = *(const short8*)&Bs[r * 32 + ko];
        }
        #pragma unroll
        for (int i = 0; i < 4; ++i)
            #pragma unroll
            for (int j = 0; j < 4; ++j) {
                acc[i][j] = __builtin_amdgcn_mfma_f32_16x16x32_bf16(afl[i], bf[j], acc[i][j], 0, 0, 0);
                acc[i][j] = __builtin_amdgcn_mfma_f32_16x16x32_bf16(afh[i], bf[j], acc[i][j], 0, 0, 0);
            }

        __syncthreads();
    }

    // epilogue: C/D layout col=lane&15, row=quad*4+reg
    #pragma unroll
    for (int j = 0; j < 4; ++j) {
        const int gc = n0 + wn * 64 + j * 16 + fm;
        const float bj = bias ? bias[gc] : 0.f;
        #pragma unroll
        for (int i = 0; i < 4; ++i) {
            #pragma unroll
            for (int r = 0; r < 4; ++r) {
                const int gr = m0 + wm * 64 + i * 16 + quad * 4 + r;
                if (gr < M) {
                    float v = acc[i][j][r] + bj;
                    if (resid) v += resid[(size_t)gr * ldC + gc];
                    if (Cbf) Cbf[(size_t)gr * ldC + gc] = f2bf_rne(v);
                    else     C  [(size_t)gr * ldC + gc] = v;
                }
            }
        }
    }
}

__device__ __forceinline__ float wave_sum(float v) {
    #pragma unroll
    for (int o = 32; o > 0; o >>= 1) v += __shfl_xor(v, o);
    return v;
}

// ---------------- CSR build (once per launch) ----------------
__global__ __launch_bounds__(256) void count_kernel(
    const int* __restrict__ dst, int* __restrict__ deg, int E)
{
    int e = blockIdx.x * 256 + threadIdx.x;
    if (e < E) atomicAdd(&deg[dst[e]], 1);
}

__global__ __launch_bounds__(1024) void scan_kernel(
    const int* __restrict__ deg, int* __restrict__ rowptr, int n)
{
    __shared__ int wsum[16];
    __shared__ int carry_s;
    const int tid = threadIdx.x;
    const int lane = tid & 63, wave = tid >> 6;
    if (tid == 0) carry_s = 0;
    __syncthreads();

    for (int base = 0; base < n; base += 1024) {
        int i = base + tid;
        int v = (i < n) ? deg[i] : 0;
        int x = v;
        #pragma unroll
        for (int o = 1; o < 64; o <<= 1) {
            int t = __shfl_up(x, o);
            if (lane >= o) x += t;
        }
        if (lane == 63) wsum[wave] = x;
        __syncthreads();
        if (wave == 0 && lane < 16) {
            int w = wsum[lane];
            #pragma unroll
            for (int o = 1; o < 16; o <<= 1) {
                int t = __shfl_up(w, o);
                if (lane >= o) w += t;
            }
            wsum[lane] = w;
        }
        __syncthreads();
        int wave_off = (wave == 0) ? 0 : wsum[wave - 1];
        int incl = x + wave_off + carry_s;
        if (i < n) rowptr[i] = incl - v;
        __syncthreads();
        if (tid == 0) carry_s += wsum[15];
        __syncthreads();
    }
    if (tid == 0) rowptr[n] = carry_s;
}

__global__ __launch_bounds__(256) void scatter_kernel(
    const int* __restrict__ dst, int* __restrict__ cursor,
    int* __restrict__ esorted, int E)
{
    int e = blockIdx.x * 256 + threadIdx.x;
    if (e < E) {
        int p = atomicAdd(&cursor[dst[e]], 1);
        esorted[p] = e;
    }
}

// ---------------- fused per-node message + aggregate (R2 structure, bf16 P) ----------------
__global__ __launch_bounds__(256) void node_agg_kernel(
    const unsigned short* __restrict__ P,   // [N,512] bf16
    const int* __restrict__ src,
    const float* __restrict__ attr,   // [E,4]
    const float* __restrict__ W3,     // [4,256]
    const float* __restrict__ be, const float* __restrict__ g1, const float* __restrict__ b1,
    const int* __restrict__ rowptr, const int* __restrict__ esorted,
    float* __restrict__ agg, int N)
{
    const int wave = threadIdx.x >> 6;
    const int lane = threadIdx.x & 63;
    const int n = blockIdx.x * 4 + wave;
    if (n >= N) return;
    const int c0 = lane * 4;

    ushort4 p1u = *(const ushort4*)(P + (size_t)n * 512 + c0);
    float p1p[4] = {bf2f(p1u.x), bf2f(p1u.y), bf2f(p1u.z), bf2f(p1u.w)};

    float w30[4], w31[4], w32[4], w33[4], bev[4], g1v[4], b1v[4];
    #pragma unroll
    for (int i = 0; i < 4; ++i) {
        const int c = c0 + i;
        w30[i] = W3[c]; w31[i] = W3[256 + c]; w32[i] = W3[512 + c]; w33[i] = W3[768 + c];
        bev[i] = be[c]; g1v[i] = g1[c]; b1v[i] = b1[c];
    }

    float acc[4] = {0.f, 0.f, 0.f, 0.f};
    const int beg = rowptr[n];
    const int end = rowptr[n + 1];

    for (int i = beg; i < end; ++i) {
        const int e = esorted[i];
        const int s = src[e];
        ushort4 psu = *(const ushort4*)(P + (size_t)s * 512 + 256 + c0);
        float psp[4] = {bf2f(psu.x), bf2f(psu.y), bf2f(psu.z), bf2f(psu.w)};
        float4 av = *(const float4*)(attr + (size_t)e * 4);

        float h[4];
        #pragma unroll
        for (int j = 0; j < 4; ++j) {
            float w = av.x * w30[j] + av.y * w31[j] + av.z * w32[j] + av.w * w33[j];
            h[j] = p1p[j] + psp[j] + w + bev[j];
        }

        float sum = wave_sum(h[0] + h[1] + h[2] + h[3]);
        const float mean = sum * (1.0f / 256.0f);
        float vs = 0.f;
        #pragma unroll
        for (int j = 0; j < 4; ++j) { float t = h[j] - mean; vs += t * t; }
        vs = wave_sum(vs);
        const float rstd = rsqrtf(vs * (1.0f / 256.0f) + 1e-5f);

        #pragma unroll
        for (int j = 0; j < 4; ++j) {
            float y = (h[j] - mean) * rstd * g1v[j] + b1v[j];
            acc[j] += y / (1.0f + __expf(-y));
        }
    }

    *(float4*)(agg + (size_t)n * 256 + c0) = make_float4(acc[0], acc[1], acc[2], acc[3]);
}

// In-place LayerNorm + SiLU over rows of u [N,256]; one wave per row. (R2 version)
__global__ __launch_bounds__(256) void ln_silu_kernel(
    float* __restrict__ u, const float* __restrict__ g, const float* __restrict__ b, int N)
{
    const int wave = threadIdx.x >> 6;
    const int lane = threadIdx.x & 63;
    const int r = blockIdx.x * 4 + wave;
    if (r >= N) return;

    float4 hv = *(const float4*)(u + (size_t)r * 256 + lane * 4);
    float h[4] = {hv.x, hv.y, hv.z, hv.w};

    float sum = wave_sum(h[0] + h[1] + h[2] + h[3]);
    const float mean = sum * (1.0f / 256.0f);
    float vs = 0.f;
    #pragma unroll
    for (int i = 0; i < 4; ++i) { float t = h[i] - mean; vs += t * t; }
    vs = wave_sum(vs);
    const float rstd = rsqrtf(vs * (1.0f / 256.0f) + 1e-5f);

    #pragma unroll
    for (int i = 0; i < 4; ++i) {
        const int c = lane * 4 + i;
        float y = (h[i] - mean) * rstd * g[c] + b[c];
        h[i] = y / (1.0f + __expf(-y));
    }
    *(float4*)(u + (size_t)r * 256 + lane * 4) = make_float4(h[0], h[1], h[2], h[3]);
}

extern "C" void kernel_launch(void* const* d_in, const int* in_sizes, int n_in,
                              void* d_out, int out_size, void* d_ws, size_t ws_size,
                              hipStream_t stream) {
    const float* mesh   = (const float*)d_in[0];
    const int*   eidx   = (const int*)  d_in[1];
    const float* eattr  = (const float*)d_in[2];
    const float* We_w   = (const float*)d_in[3];
    const float* We_b   = (const float*)d_in[4];
    const float* ln1_g  = (const float*)d_in[5];
    const float* ln1_b  = (const float*)d_in[6];
    const float* Wn1_w  = (const float*)d_in[7];
    const float* Wn1_b  = (const float*)d_in[8];
    const float* ln2_g  = (const float*)d_in[9];
    const float* ln2_b  = (const float*)d_in[10];
    const float* Wn2_w  = (const float*)d_in[11];
    const float* Wn2_b  = (const float*)d_in[12];

    const int N = NNODES, E = NEDGES;

    float* x = (float*)d_out;                         // [N,256] fp32
    unsigned short* P = (unsigned short*)d_ws;        // [N,512] bf16
    float* u = (float*)d_ws;                          // [N,256] fp32, aliases P (same extent)
    float* agg = (float*)((char*)d_ws + (size_t)N * 512 * 2);  // [N,256] fp32
    int*   deg     = (int*)(agg + (size_t)N * 256);
    int*   rowptr  = deg + N;
    int*   cursor  = rowptr + (N + 1);
    int*   esorted = cursor + N;                      // E
    uintptr_t wp = (uintptr_t)(esorted + E);
    wp = (wp + 63) & ~(uintptr_t)63;
    unsigned short* BTe  = (unsigned short*)wp;            // [6][512][256]
    unsigned short* BTn1 = BTe  + (size_t)6 * 512 * 256;   // [6][256][512]
    unsigned short* BTn2 = BTn1 + (size_t)6 * 256 * 512;   // [6][256][256]

    const int* src = eidx;
    const int* dst = eidx + E;

    hipMemcpyAsync(x, mesh, (size_t)N * 256 * sizeof(float),
                   hipMemcpyDeviceToDevice, stream);

    // ---- weight prep ----
    wprep_kernel<<<dim3(8, 8, 12), 256, 0, stream>>>(
        We_w, BTe, 256, 256, (size_t)516 * 256, (size_t)256 * 256, 2);
    wprep_kernel<<<dim3(8, 16, 6), 256, 0, stream>>>(
        Wn1_w, BTn1, 512, 256, (size_t)512 * 256, 0, 1);
    wprep_kernel<<<dim3(8, 8, 6), 256, 0, stream>>>(
        Wn2_w, BTn2, 256, 256, (size_t)256 * 256, 0, 1);

    // ---- CSR build ----
    hipMemsetAsync(deg, 0, (size_t)N * sizeof(int), stream);
    count_kernel<<<(E + 255) / 256, 256, 0, stream>>>(dst, deg, E);
    scan_kernel<<<1, 1024, 0, stream>>>(deg, rowptr, N);
    hipMemcpyAsync(cursor, rowptr, (size_t)N * sizeof(int),
                   hipMemcpyDeviceToDevice, stream);
    scatter_kernel<<<(E + 255) / 256, 256, 0, stream>>>(dst, cursor, esorted, E);

    const int mblocks = (N + 127) / 128;
    const int node_blocks = (N + 3) / 4;

    for (int l = 0; l < NLAYERS; ++l) {
        const float* W3  = We_w + (size_t)l * 516 * 256 + (size_t)512 * 256;
        const float* be  = We_b  + (size_t)l * 256;
        const float* g1  = ln1_g + (size_t)l * 256;
        const float* b1  = ln1_b + (size_t)l * 256;
        const float* bn1 = Wn1_b + (size_t)l * 256;
        const float* g2  = ln2_g + (size_t)l * 256;
        const float* b2  = ln2_b + (size_t)l * 256;
        const float* bn2 = Wn2_b + (size_t)l * 256;
        const unsigned short* bte  = BTe  + (size_t)l * 512 * 256;
        const unsigned short* btn1 = BTn1 + (size_t)l * 256 * 512;
        const unsigned short* btn2 = BTn2 + (size_t)l * 256 * 256;

        // P = x @ [W1|W2] -> [N,512] bf16
        gemm_mfma<<<dim3(mblocks, 4), 256, 0, stream>>>(
            x, nullptr, bte, nullptr, nullptr, nullptr, P, N, 256, 512);
        // agg
        node_agg_kernel<<<node_blocks, 256, 0, stream>>>(
            P, src, eattr, W3, be, g1, b1, rowptr, esorted, agg, N);
        // u = [x | agg] @ Wn1 + bn1  (u aliases P; P dead)
        gemm_mfma<<<dim3(mblocks, 2), 256, 0, stream>>>(
            x, agg, btn1, bn1, nullptr, u, nullptr, N, 512, 256);
        // u = silu(LN(u)) in place
        ln_silu_kernel<<<node_blocks, 256, 0, stream>>>(u, g2, b2, N);
        // x = x + u @ Wn2 + bn2
        gemm_mfma<<<dim3(mblocks, 2), 256, 0, stream>>>(
            u, nullptr, btn2, bn2, x, x, nullptr, N, 256, 256);
    }
}